// Round 7
// baseline (964.331 us; speedup 1.0000x reference)
//
#include <hip/hip_runtime.h>
#include <hip/hip_cooperative_groups.h>

namespace cg = cooperative_groups;

// ---------- helpers ----------
__device__ inline unsigned short f2bf(float f) {
    unsigned u = __float_as_uint(f);
    unsigned r = u + 0x7FFF + ((u >> 16) & 1);   // round-to-nearest-even
    return (unsigned short)(r >> 16);
}
__device__ inline unsigned pk2bf(unsigned lo_bits, unsigned hi_bits) {
    unsigned rl = lo_bits + 0x7FFF + ((lo_bits >> 16) & 1);
    unsigned rh = hi_bits + 0x7FFF + ((hi_bits >> 16) & 1);
    return (rl >> 16) | (rh & 0xFFFF0000u);
}
__device__ inline float b2f(unsigned short h) { return __uint_as_float(((unsigned)h) << 16); }
__device__ inline float bfu_lo(unsigned u) { return __uint_as_float(u << 16); }
__device__ inline float bfu_hi(unsigned u) { return __uint_as_float(u & 0xFFFF0000u); }

typedef short bf16x8 __attribute__((ext_vector_type(8)));
typedef float f32x4  __attribute__((ext_vector_type(4)));

#define BN_EPS 1e-5f

// flags[0]=edges_are_int64, flags[1]=x_is_bf16, flags[2]=W_is_bf16, flags[3]=params_are_bf16

__device__ inline int edge_at(const int* ei32, int e64, long long idx) {
    if (e64) return (int)((const long long*)ei32)[idx];
    return ei32[idx];
}
__device__ inline float ldf(const void* p, int idx, int isbf) {
    return isbf ? b2f(((const unsigned short*)p)[idx]) : ((const float*)p)[idx];
}

// ---------- shared device bodies ----------
__device__ inline void hist_body(const int* ei32, int E, int e64, int N,
                                 int* cnt, int* rank, long long i) {
    if (i < E) {
        int s = edge_at(ei32, e64, i);
        int d = edge_at(ei32, e64, (long long)E + i);
        if ((unsigned)s < (unsigned)N && (unsigned)d < (unsigned)N)
            rank[i] = atomicAdd(&cnt[d], 1);
    }
}

// row-major x -> bf16 copy/convert (8 elems / thread)
__device__ inline void cvt_body_row(long long i, const unsigned* xw,
                                    unsigned short* xbf, int xisbf, long long nv) {
    if (i >= nv) return;
    if (xisbf) {
        ((uint4*)xbf)[i] = ((const uint4*)xw)[i];
    } else {
        const uint4* xp = (const uint4*)xw;
        uint4 a = xp[2 * i], b = xp[2 * i + 1];
        uint4 o;
        o.x = pk2bf(a.x, a.y);
        o.y = pk2bf(a.z, a.w);
        o.z = pk2bf(b.x, b.y);
        o.w = pk2bf(b.z, b.w);
        ((uint4*)xbf)[i] = o;
    }
}

__device__ inline void place_body(const int* ei32, int E, int e64, int N,
                                  const int* row_off, const int* rank, int* ssrc,
                                  long long i) {
    if (i < E) {
        int s = edge_at(ei32, e64, i);
        int d = edge_at(ei32, e64, (long long)E + i);
        if ((unsigned)s < (unsigned)N && (unsigned)d < (unsigned)N)
            ssrc[row_off[d] + rank[i]] = s;
    }
}

__device__ inline void prepw_body(const void* W, const void* b,
                                  const void* gamma, const void* beta,
                                  const void* rmean, const void* rvar,
                                  const int* flags,
                                  float* Wf, unsigned short* Wt,
                                  float* scale, float* shift, int k, int n) {
    int wbf = flags[2], pbf = flags[3];
    float wv = ldf(W, k * 256 + n, wbf);
    Wf[k * 256 + n] = wv;
    Wt[n * 256 + k] = f2bf(wv);
    if (k == 0) {
        float s = ldf(gamma, n, pbf) * rsqrtf(ldf(rvar, n, pbf) + BN_EPS);
        scale[n] = s;
        shift[n] = (ldf(b, n, pbf) - ldf(rmean, n, pbf)) * s + ldf(beta, n, pbf);
    }
}

// one row of the aggregation (R6-proven bf16 shuffle gather) — no early return
__device__ inline void agg_row_bf(const unsigned short* xs, const int* row_off,
                                  const int* ssrc, const float* dinv,
                                  unsigned short* aggw, int i, int lane) {
    int half = lane >> 5, hl = lane & 31;
    int beg = row_off[i], end = row_off[i + 1];
    float di = dinv[i];
    float acc[8] = {};
    for (int base = beg; base < end; base += 64) {
        int cnt = end - base; if (cnt > 64) cnt = 64;
        int sl = 0; float dl = 0.f;
        if (lane < cnt) { sl = ssrc[base + lane]; dl = dinv[sl]; }
        for (int j = 0; j < cnt; j += 8) {
            int jj0 = j + half, jj1 = j + 2 + half, jj2 = j + 4 + half, jj3 = j + 6 + half;
            int   s0 = __shfl(sl, jj0 & 63), s1 = __shfl(sl, jj1 & 63);
            int   s2 = __shfl(sl, jj2 & 63), s3 = __shfl(sl, jj3 & 63);
            float d0 = __shfl(dl, jj0 & 63), d1 = __shfl(dl, jj1 & 63);
            float d2 = __shfl(dl, jj2 & 63), d3 = __shfl(dl, jj3 & 63);
            if (jj0 >= cnt) d0 = 0.f;
            if (jj1 >= cnt) d1 = 0.f;
            if (jj2 >= cnt) d2 = 0.f;
            if (jj3 >= cnt) d3 = 0.f;
            uint4 v0 = ((const uint4*)(xs + (size_t)s0 * 256))[hl];
            uint4 v1 = ((const uint4*)(xs + (size_t)s1 * 256))[hl];
            uint4 v2 = ((const uint4*)(xs + (size_t)s2 * 256))[hl];
            uint4 v3 = ((const uint4*)(xs + (size_t)s3 * 256))[hl];
            acc[0] += d0 * bfu_lo(v0.x); acc[1] += d0 * bfu_hi(v0.x);
            acc[2] += d0 * bfu_lo(v0.y); acc[3] += d0 * bfu_hi(v0.y);
            acc[4] += d0 * bfu_lo(v0.z); acc[5] += d0 * bfu_hi(v0.z);
            acc[6] += d0 * bfu_lo(v0.w); acc[7] += d0 * bfu_hi(v0.w);
            acc[0] += d1 * bfu_lo(v1.x); acc[1] += d1 * bfu_hi(v1.x);
            acc[2] += d1 * bfu_lo(v1.y); acc[3] += d1 * bfu_hi(v1.y);
            acc[4] += d1 * bfu_lo(v1.z); acc[5] += d1 * bfu_hi(v1.z);
            acc[6] += d1 * bfu_lo(v1.w); acc[7] += d1 * bfu_hi(v1.w);
            acc[0] += d2 * bfu_lo(v2.x); acc[1] += d2 * bfu_hi(v2.x);
            acc[2] += d2 * bfu_lo(v2.y); acc[3] += d2 * bfu_hi(v2.y);
            acc[4] += d2 * bfu_lo(v2.z); acc[5] += d2 * bfu_hi(v2.z);
            acc[6] += d2 * bfu_lo(v2.w); acc[7] += d2 * bfu_hi(v2.w);
            acc[0] += d3 * bfu_lo(v3.x); acc[1] += d3 * bfu_hi(v3.x);
            acc[2] += d3 * bfu_lo(v3.y); acc[3] += d3 * bfu_hi(v3.y);
            acc[4] += d3 * bfu_lo(v3.z); acc[5] += d3 * bfu_hi(v3.z);
            acc[6] += d3 * bfu_lo(v3.w); acc[7] += d3 * bfu_hi(v3.w);
        }
    }
    #pragma unroll
    for (int f = 0; f < 8; f++) acc[f] += __shfl(acc[f], lane ^ 32);
    if (half == 0) {
        uint4 v = ((const uint4*)(xs + (size_t)i * 256))[hl];
        float sv[8];
        sv[0] = bfu_lo(v.x); sv[1] = bfu_hi(v.x); sv[2] = bfu_lo(v.y); sv[3] = bfu_hi(v.y);
        sv[4] = bfu_lo(v.z); sv[5] = bfu_hi(v.z); sv[6] = bfu_lo(v.w); sv[7] = bfu_hi(v.w);
        unsigned short o[8];
        #pragma unroll
        for (int f = 0; f < 8; f++) o[f] = f2bf((acc[f] + di * sv[f]) * di);
        uint4 pk;
        pk.x = (unsigned)o[0] | ((unsigned)o[1] << 16);
        pk.y = (unsigned)o[2] | ((unsigned)o[3] << 16);
        pk.z = (unsigned)o[4] | ((unsigned)o[5] << 16);
        pk.w = (unsigned)o[6] | ((unsigned)o[7] << 16);
        ((uint4*)(aggw + (size_t)i * 256))[hl] = pk;
    }
}

// 32-row MFMA GEMM tile; A in LDS (1 barrier), B direct from global (L2/L1-hot)
__device__ inline void gemm_tile32(const unsigned short* agg, float* out,
                                   const unsigned short* Wt, const float* scale,
                                   const float* shift, int N, int m0,
                                   unsigned short* Asm, int t) {
    for (int rep = 0; rep < 4; rep++) {
        int idx = rep * 256 + t;
        int r = idx >> 5, c8 = idx & 31;
        int m = m0 + r;
        uint4 v = make_uint4(0u, 0u, 0u, 0u);
        if (m < N) v = ((const uint4*)(agg + (size_t)m * 256))[c8];
        *(uint4*)&Asm[r * 264 + c8 * 8] = v;
    }
    __syncthreads();
    f32x4 acc[2][4] = {};
    int wv = t >> 6, lane = t & 63;
    int wc = wv * 64, lm = lane & 15, q = lane >> 4;
    for (int k0 = 0; k0 < 256; k0 += 32) {
        bf16x8 af[2], bfr[4];
        for (int c = 0; c < 4; c++)
            bfr[c] = *(const bf16x8*)&Wt[(size_t)(wc + c * 16 + lm) * 256 + k0 + q * 8];
        for (int r = 0; r < 2; r++)
            af[r] = *(const bf16x8*)&Asm[(r * 16 + lm) * 264 + k0 + q * 8];
        for (int r = 0; r < 2; r++)
            for (int c = 0; c < 4; c++)
                acc[r][c] = __builtin_amdgcn_mfma_f32_16x16x32_bf16(af[r], bfr[c], acc[r][c], 0, 0, 0);
    }
    for (int c = 0; c < 4; c++) {
        int n = wc + c * 16 + lm;
        float sc = scale[n], sh = shift[n];
        for (int r = 0; r < 2; r++)
            for (int e = 0; e < 4; e++) {
                int m = m0 + r * 16 + q * 4 + e;
                if (m < N) {
                    float v = acc[r][c][e] * sc + sh;
                    out[(size_t)m * 256 + n] = fmaxf(v, 0.f);
                }
            }
    }
    __syncthreads();   // before next tile restages Asm
}

// ---------- THE mega-kernel: all phases, grid.sync between ----------
// __launch_bounds__(256, 4): VGPR<=128, >=4 blocks/CU -> grid 1024 guaranteed
// co-resident (LDS ~19KB/block -> 4/CU fits 160KB). No early returns anywhere.
__global__ __launch_bounds__(256, 4) void k_mega(
        const int* __restrict__ ei, int E, int N, int C,
        int* __restrict__ flags, int* __restrict__ deg, int* __restrict__ rank,
        int* __restrict__ row_off, int* __restrict__ cursor,
        int* __restrict__ bsum, float* __restrict__ dinv, int* __restrict__ ssrc,
        const unsigned* __restrict__ xw, unsigned short* __restrict__ xbf,
        const void* __restrict__ W, const void* __restrict__ b,
        const void* __restrict__ gamma, const void* __restrict__ beta,
        const void* __restrict__ rmean, const void* __restrict__ rvar,
        float* __restrict__ Wf, unsigned short* __restrict__ Wt,
        float* __restrict__ scale, float* __restrict__ shift,
        unsigned short* __restrict__ aggw, float* __restrict__ out) {
    cg::grid_group grid = cg::this_grid();
    __shared__ unsigned short Asm[32 * 264];
    __shared__ int sm[256];
    __shared__ int bs[256];
    __shared__ int s_nz, s_xc, s_wc;

    int bid = blockIdx.x, t = threadIdx.x;
    int gstride = gridDim.x * 256;
    long long gid = (long long)bid * 256 + t;

    // ---- P1: zero deg + detect (block 0) ----
    for (long long i = gid; i < N; i += gstride) deg[i] = 0;
    if (bid == 0) {
        if (t == 0) { s_nz = 0; s_xc = 0; s_wc = 0; }
        __syncthreads();
        int nz = 0, xc = 0, wc = 0;
        for (int i = t; i < 1024; i += 256)
            if (ei[2 * i + 1] != 0) nz = 1;
        for (int i = t; i < 4096; i += 256) {
            unsigned ex = (xw[i] >> 7) & 0xFF;
            if (ex >= 90 && ex <= 150) xc++;
            unsigned ew = (((const unsigned*)W)[i] >> 7) & 0xFF;
            if (ew >= 90 && ew <= 150) wc++;
        }
        atomicAdd(&s_xc, xc);
        atomicAdd(&s_wc, wc);
        if (nz) atomicOr(&s_nz, 1);
        __syncthreads();
        if (t == 0) {
            flags[0] = s_nz ? 0 : 1;
            int xbf_ = (s_xc > 3686) ? 1 : 0;
            flags[1] = xbf_;
            flags[2] = (s_wc > 3686) ? 1 : 0;
            unsigned g = ((const unsigned*)gamma)[0];
            flags[3] = (g == 0x3F803F80u) ? 1 : ((g == 0x3F800000u) ? 0 : xbf_);
        }
    }
    grid.sync();

    // ---- P2: histogram+rank | x->bf16 cvt | W prep ----
    {
        int e64 = flags[0];
        for (long long i = gid; i < E; i += gstride)
            hist_body(ei, E, e64, N, deg, rank, i);
        int xisbf = flags[1];
        long long nv = (long long)N * 32;
        for (long long i = gid; i < nv; i += gstride)
            cvt_body_row(i, xw, xbf, xisbf, nv);
        for (int k = bid; k < 256; k += gridDim.x)
            prepw_body(W, b, gamma, beta, rmean, rvar, flags, Wf, Wt, scale, shift, k, t);
    }
    grid.sync();

    // ---- P3a: per-chunk reduce (blocks 0..255) ----
    if (bid < 256) {
        int i = bid * C + t;
        int v = (t < C && i < N) ? deg[i] : 0;
        sm[t] = v;
        __syncthreads();
        for (int d = 128; d > 0; d >>= 1) {
            if (t < d) sm[t] += sm[t + d];
            __syncthreads();
        }
        if (t == 0) bsum[bid] = sm[0];
    }
    grid.sync();

    // ---- P3b: merged scan (blocks 0..255) ----
    if (bid < 256) {
        bs[t] = bsum[t];
        int i = bid * C + t;
        int v = (t < C && i < N) ? deg[i] : 0;
        sm[t] = v;
        for (int d = 1; d < 256; d <<= 1) {
            __syncthreads();
            int u  = (t >= d) ? bs[t - d] : 0;
            int u2 = (t >= d) ? sm[t - d] : 0;
            __syncthreads();
            bs[t] += u;
            sm[t] += u2;
        }
        __syncthreads();
        if (bid == 0 && t == 255) row_off[N] = bs[255];
        int bbase = (bid > 0) ? bs[bid - 1] : 0;
        if (t < C && i < N) {
            int off = bbase + sm[t] - v;
            row_off[i] = off;
            cursor[i]  = off;
            dinv[i]    = rsqrtf((float)(v + 1));   // +1 self loop
        }
    }
    grid.sync();

    // ---- P4: place edges into CSR ----
    {
        int e64 = flags[0];
        for (long long i = gid; i < E; i += gstride)
            place_body(ei, E, e64, N, row_off, rank, ssrc, i);
    }
    grid.sync();

    // ---- P5: aggregation ----
    {
        int wave = t >> 6, lane = t & 63;
        int ngrp = (N + 3) >> 2;
        for (int g = bid; g < ngrp; g += gridDim.x) {
            int i = g * 4 + wave;
            if (i < N)
                agg_row_bf(xbf, row_off, ssrc, dinv, aggw, i, lane);
        }
    }
    grid.sync();

    // ---- P6: MFMA GEMM + BN + ReLU ----
    {
        int ntile = (N + 31) >> 5;
        for (int mt = bid; mt < ntile; mt += gridDim.x)
            gemm_tile32(aggw, out, Wt, scale, shift, N, mt * 32, Asm, t);
    }
}

// ======================================================================
// Fallback path: R6-proven separate kernels (used if cooperative launch
// is unavailable or workspace too small for tier A).
// ======================================================================

__global__ void k_init(int* __restrict__ zb, int zwords,
                       const int* __restrict__ ei32,
                       const unsigned* __restrict__ xw,
                       const unsigned* __restrict__ Ww,
                       const unsigned* __restrict__ gw,
                       int* __restrict__ flags) {
    int gid = blockIdx.x * 256 + threadIdx.x;
    if (gid < zwords) zb[gid] = 0;
    if (blockIdx.x == 0) {
        __shared__ int s_nz, s_xc, s_wc;
        int t = threadIdx.x;
        if (t == 0) { s_nz = 0; s_xc = 0; s_wc = 0; }
        __syncthreads();
        int nz = 0, xc = 0, wc = 0;
        for (int i = t; i < 1024; i += 256)
            if (ei32[2 * i + 1] != 0) nz = 1;
        for (int i = t; i < 4096; i += 256) {
            unsigned ex = (xw[i] >> 7) & 0xFF;
            if (ex >= 90 && ex <= 150) xc++;
            unsigned ew = (Ww[i] >> 7) & 0xFF;
            if (ew >= 90 && ew <= 150) wc++;
        }
        atomicAdd(&s_xc, xc);
        atomicAdd(&s_wc, wc);
        if (nz) atomicOr(&s_nz, 1);
        __syncthreads();
        if (t == 0) {
            flags[0] = s_nz ? 0 : 1;
            int xbf = (s_xc > 3686) ? 1 : 0;
            int wbf = (s_wc > 3686) ? 1 : 0;
            flags[1] = xbf;
            flags[2] = wbf;
            unsigned g = gw[0];
            flags[3] = (g == 0x3F803F80u) ? 1 : ((g == 0x3F800000u) ? 0 : xbf);
        }
    }
}

__global__ void k_hist_cvt(const int* __restrict__ ei32, int E, const int* __restrict__ flags,
                           int N, int* __restrict__ cnt, int* __restrict__ rank,
                           const unsigned* __restrict__ xw, unsigned short* __restrict__ xbf,
                           int do_cvt) {
    long long i = (long long)blockIdx.x * blockDim.x + threadIdx.x;
    hist_body(ei32, E, flags[0], N, cnt, rank, i);
    if (do_cvt) cvt_body_row(i, xw, xbf, flags[1], (long long)N * 32);
}

__global__ void k_scan1(const int* __restrict__ cnt, int N, int C, int* __restrict__ bsum) {
    __shared__ int sm[256];
    int b = blockIdx.x, t = threadIdx.x;
    int i = b * C + t;
    int v = (t < C && i < N) ? cnt[i] : 0;
    sm[t] = v;
    __syncthreads();
    for (int d = 128; d > 0; d >>= 1) {
        if (t < d) sm[t] += sm[t + d];
        __syncthreads();
    }
    if (t == 0) bsum[b] = sm[0];
}

__global__ void k_scan3(const int* __restrict__ cnt, const int* __restrict__ bsum,
                        int N, int C, int* __restrict__ row_off,
                        int* __restrict__ cursor, float* __restrict__ dinv) {
    __shared__ int sm[256];
    __shared__ int bs[256];
    int b = blockIdx.x, t = threadIdx.x;
    bs[t] = bsum[t];
    int i = b * C + t;
    int v = (t < C && i < N) ? cnt[i] : 0;
    sm[t] = v;
    for (int d = 1; d < 256; d <<= 1) {
        __syncthreads();
        int u  = (t >= d) ? bs[t - d] : 0;
        int u2 = (t >= d) ? sm[t - d] : 0;
        __syncthreads();
        bs[t] += u;
        sm[t] += u2;
    }
    __syncthreads();
    if (b == 0 && t == 255) row_off[N] = bs[255];
    int bbase = (b > 0) ? bs[b - 1] : 0;
    if (t < C && i < N) {
        int off = bbase + sm[t] - v;
        row_off[i] = off;
        cursor[i]  = off;
        dinv[i]    = rsqrtf((float)(v + 1));
    }
}

__global__ void k_fuse_pp(const int* __restrict__ ei32, int E, const int* __restrict__ flags,
                          int N, const int* __restrict__ row_off, const int* __restrict__ rank,
                          int* __restrict__ ssrc,
                          const void* __restrict__ W, const void* __restrict__ b,
                          const void* __restrict__ gamma, const void* __restrict__ beta,
                          const void* __restrict__ rmean, const void* __restrict__ rvar,
                          float* __restrict__ Wf, unsigned short* __restrict__ Wt,
                          float* __restrict__ scale, float* __restrict__ shift) {
    int bb = blockIdx.x;
    if (bb < 256) {
        prepw_body(W, b, gamma, beta, rmean, rvar, flags, Wf, Wt, scale, shift,
                   bb, threadIdx.x);
    } else {
        long long i = (long long)(bb - 256) * 256 + threadIdx.x;
        place_body(ei32, E, flags[0], N, row_off, rank, ssrc, i);
    }
}

__global__ void k_scatter(const int* __restrict__ ei32, int E, const int* __restrict__ flags,
                          int N, int* __restrict__ cursor, int* __restrict__ ssrc) {
    int i = blockIdx.x * blockDim.x + threadIdx.x;
    if (i < E) {
        int e64 = flags[0];
        int s = edge_at(ei32, e64, i);
        int d = edge_at(ei32, e64, (long long)E + i);
        if ((unsigned)s < (unsigned)N && (unsigned)d < (unsigned)N) {
            int pos = atomicAdd(&cursor[d], 1);
            ssrc[pos] = s;
        }
    }
}

__global__ __launch_bounds__(256) void k_agg_bf(
        const void* __restrict__ xraw, const int* __restrict__ flags,
        const int* __restrict__ row_off, const int* __restrict__ ssrc,
        const float* __restrict__ dinv, unsigned short* __restrict__ aggw,
        int N, int force_bf) {
    int wave = threadIdx.x >> 6;
    int lane = threadIdx.x & 63;
    int half = lane >> 5, hl = lane & 31;
    int i = blockIdx.x * 4 + wave;
    if (i >= N) return;
    int xbf = force_bf ? 1 : flags[1];
    if (xbf) {
        agg_row_bf((const unsigned short*)xraw, row_off, ssrc, dinv, aggw, i, lane);
        return;
    }
    // f32 input path
    int beg = row_off[i], end = row_off[i + 1];
    float di = dinv[i];
    float acc[8] = {};
    const float* xf = (const float*)xraw;
    for (int base = beg; base < end; base += 64) {
        int cnt = end - base; if (cnt > 64) cnt = 64;
        int sl = 0; float dl = 0.f;
        if (lane < cnt) { sl = ssrc[base + lane]; dl = dinv[sl]; }
        for (int j = 0; j < cnt; j += 4) {
            int jj0 = j + half, jj1 = j + 2 + half;
            int   s0 = __shfl(sl, jj0 & 63);
            float d0 = __shfl(dl, jj0 & 63);
            int   s1 = __shfl(sl, jj1 & 63);
            float d1 = __shfl(dl, jj1 & 63);
            if (jj0 >= cnt) d0 = 0.f;
            if (jj1 >= cnt) d1 = 0.f;
            const float4* p0 = (const float4*)(xf + (size_t)s0 * 256 + hl * 8);
            const float4* p1 = (const float4*)(xf + (size_t)s1 * 256 + hl * 8);
            float4 a0 = p0[0], a1 = p0[1];
            float4 b0 = p1[0], b1 = p1[1];
            acc[0] += d0 * a0.x; acc[1] += d0 * a0.y;
            acc[2] += d0 * a0.z; acc[3] += d0 * a0.w;
            acc[4] += d0 * a1.x; acc[5] += d0 * a1.y;
            acc[6] += d0 * a1.z; acc[7] += d0 * a1.w;
            acc[0] += d1 * b0.x; acc[1] += d1 * b0.y;
            acc[2] += d1 * b0.z; acc[3] += d1 * b0.w;
            acc[4] += d1 * b1.x; acc[5] += d1 * b1.y;
            acc[6] += d1 * b1.z; acc[7] += d1 * b1.w;
        }
    }
    #pragma unroll
    for (int f = 0; f < 8; f++) acc[f] += __shfl(acc[f], lane ^ 32);
    if (half == 0) {
        const float4* vp = (const float4*)(xf + (size_t)i * 256 + hl * 8);
        float4 v0 = vp[0], v1 = vp[1];
        float sv[8] = {v0.x, v0.y, v0.z, v0.w, v1.x, v1.y, v1.z, v1.w};
        unsigned short o[8];
        #pragma unroll
        for (int f = 0; f < 8; f++) o[f] = f2bf((acc[f] + di * sv[f]) * di);
        uint4 pk;
        pk.x = (unsigned)o[0] | ((unsigned)o[1] << 16);
        pk.y = (unsigned)o[2] | ((unsigned)o[3] << 16);
        pk.z = (unsigned)o[4] | ((unsigned)o[5] << 16);
        pk.w = (unsigned)o[6] | ((unsigned)o[7] << 16);
        ((uint4*)(aggw + (size_t)i * 256))[hl] = pk;
    }
}

__global__ __launch_bounds__(256) void k_gemm_mfma(
        const unsigned short* __restrict__ agg, float* __restrict__ out,
        const unsigned short* __restrict__ Wt,
        const float* __restrict__ scale, const float* __restrict__ shift, int N) {
    __shared__ unsigned short Asm[64 * 264];
    int t = threadIdx.x;
    int m0 = blockIdx.x * 64;
    for (int rep = 0; rep < 8; rep++) {
        int idx = rep * 256 + t;
        int r = idx >> 5, c8 = idx & 31;
        int m = m0 + r;
        uint4 v = make_uint4(0u, 0u, 0u, 0u);
        if (m < N) v = ((const uint4*)(agg + (size_t)m * 256))[c8];
        *(uint4*)&Asm[r * 264 + c8 * 8] = v;
    }
    __syncthreads();
    f32x4 acc[4][4] = {};
    int wv = t >> 6, lane = t & 63;
    int wc = wv * 64;
    int lm = lane & 15, q = lane >> 4;
    for (int k0 = 0; k0 < 256; k0 += 32) {
        bf16x8 af[4], bfr[4];
        for (int c = 0; c < 4; c++)
            bfr[c] = *(const bf16x8*)&Wt[(size_t)(wc + c * 16 + lm) * 256 + k0 + q * 8];
        for (int r = 0; r < 4; r++)
            af[r] = *(const bf16x8*)&Asm[(r * 16 + lm) * 264 + k0 + q * 8];
        for (int r = 0; r < 4; r++)
            for (int c = 0; c < 4; c++)
                acc[r][c] = __builtin_amdgcn_mfma_f32_16x16x32_bf16(af[r], bfr[c], acc[r][c], 0, 0, 0);
    }
    for (int c = 0; c < 4; c++) {
        int n = wc + c * 16 + lm;
        float sc = scale[n], sh = shift[n];
        for (int r = 0; r < 4; r++)
            for (int e = 0; e < 4; e++) {
                int m = m0 + r * 16 + q * 4 + e;
                if (m < N) {
                    float v = acc[r][c][e] * sc + sh;
                    out[(size_t)m * 256 + n] = fmaxf(v, 0.f);
                }
            }
    }
}

__global__ __launch_bounds__(256) void k_agg(
        const void* __restrict__ xraw, const int* __restrict__ flags,
        const int* __restrict__ row_off, const int* __restrict__ ssrc,
        const float* __restrict__ dinv, float* __restrict__ out, int N) {
    int wave = threadIdx.x >> 6;
    int lane = threadIdx.x & 63;
    int i = blockIdx.x * 4 + wave;
    if (i >= N) return;
    int beg = row_off[i], end = row_off[i + 1];
    float di = dinv[i];
    float a0, a1, a2, a3;
    if (flags[1]) {
        const unsigned short* xs = (const unsigned short*)xraw;
        uint2 sv = ((const uint2*)(xs + (size_t)i * 256))[lane];
        a0 = di * bfu_lo(sv.x); a1 = di * bfu_hi(sv.x);
        a2 = di * bfu_lo(sv.y); a3 = di * bfu_hi(sv.y);
        for (int base = beg; base < end; base += 64) {
            int cnt = end - base; if (cnt > 64) cnt = 64;
            int sl = 0; float dl = 0.f;
            if (lane < cnt) { sl = ssrc[base + lane]; dl = dinv[sl]; }
            for (int j = 0; j < cnt; j++) {
                int   s  = __shfl(sl, j);
                float ds = __shfl(dl, j);
                uint2 v = ((const uint2*)(xs + (size_t)s * 256))[lane];
                a0 += ds * bfu_lo(v.x); a1 += ds * bfu_hi(v.x);
                a2 += ds * bfu_lo(v.y); a3 += ds * bfu_hi(v.y);
            }
        }
    } else {
        const float* xf = (const float*)xraw;
        float4 sv = ((const float4*)(xf + (size_t)i * 256))[lane];
        a0 = di * sv.x; a1 = di * sv.y; a2 = di * sv.z; a3 = di * sv.w;
        for (int base = beg; base < end; base += 64) {
            int cnt = end - base; if (cnt > 64) cnt = 64;
            int sl = 0; float dl = 0.f;
            if (lane < cnt) { sl = ssrc[base + lane]; dl = dinv[sl]; }
            for (int j = 0; j < cnt; j++) {
                int   s  = __shfl(sl, j);
                float ds = __shfl(dl, j);
                float4 v = ((const float4*)(xf + (size_t)s * 256))[lane];
                a0 += ds * v.x; a1 += ds * v.y; a2 += ds * v.z; a3 += ds * v.w;
            }
        }
    }
    float4 o;
    o.x = a0 * di; o.y = a1 * di; o.z = a2 * di; o.w = a3 * di;
    ((float4*)(out + (size_t)i * 256))[lane] = o;
}

__global__ __launch_bounds__(256) void k_gemm32(
        float* __restrict__ io, const float* __restrict__ Wf,
        const float* __restrict__ scale, const float* __restrict__ shift, int N) {
    __shared__ float Asm[64][17];
    __shared__ float Wsm[16][260];
    int t = threadIdx.x;
    int m0 = blockIdx.x * 64;
    int tx = t & 15, ty = t >> 4;
    float acc[4][16] = {};
    for (int k0 = 0; k0 < 256; k0 += 16) {
        __syncthreads();
        {
            int r = t >> 2, c = (t & 3) * 4;
            int m = m0 + r;
            float4 v = make_float4(0.f, 0.f, 0.f, 0.f);
            if (m < N) v = *(const float4*)&io[(size_t)m * 256 + k0 + c];
            Asm[r][c] = v.x; Asm[r][c + 1] = v.y; Asm[r][c + 2] = v.z; Asm[r][c + 3] = v.w;
        }
        {
            int kk = t >> 4, nn = (t & 15) * 16;
            const float4* g = (const float4*)&Wf[(size_t)(k0 + kk) * 256 + nn];
            float4 w0 = g[0], w1 = g[1], w2 = g[2], w3 = g[3];
            *(float4*)&Wsm[kk][nn]      = w0;
            *(float4*)&Wsm[kk][nn + 4]  = w1;
            *(float4*)&Wsm[kk][nn + 8]  = w2;
            *(float4*)&Wsm[kk][nn + 12] = w3;
        }
        __syncthreads();
        #pragma unroll
        for (int kk = 0; kk < 16; kk++) {
            float av[4] = {Asm[ty*4+0][kk], Asm[ty*4+1][kk], Asm[ty*4+2][kk], Asm[ty*4+3][kk]};
            float4 b0 = *(const float4*)&Wsm[kk][tx * 16];
            float4 b1 = *(const float4*)&Wsm[kk][tx * 16 + 4];
            float4 b2 = *(const float4*)&Wsm[kk][tx * 16 + 8];
            float4 b3 = *(const float4*)&Wsm[kk][tx * 16 + 12];
            float bv[16] = {b0.x,b0.y,b0.z,b0.w, b1.x,b1.y,b1.z,b1.w,
                            b2.x,b2.y,b2.z,b2.w, b3.x,b3.y,b3.z,b3.w};
            #pragma unroll
            for (int i = 0; i < 4; i++)
                #pragma unroll
                for (int j = 0; j < 16; j++)
                    acc[i][j] = fmaf(av[i], bv[j], acc[i][j]);
        }
    }
    float sc[16], sh[16];
    #pragma unroll
    for (int j = 0; j < 16; j++) { sc[j] = scale[tx * 16 + j]; sh[j] = shift[tx * 16 + j]; }
    for (int i = 0; i < 4; i++) {
        int m = m0 + ty * 4 + i;
        if (m < N) {
            #pragma unroll
            for (int j4 = 0; j4 < 4; j4++) {
                float4 o;
                o.x = fmaxf(acc[i][j4*4+0] * sc[j4*4+0] + sh[j4*4+0], 0.f);
                o.y = fmaxf(acc[i][j4*4+1] * sc[j4*4+1] + sh[j4*4+1], 0.f);
                o.z = fmaxf(acc[i][j4*4+2] * sc[j4*4+2] + sh[j4*4+2], 0.f);
                o.w = fmaxf(acc[i][j4*4+3] * sc[j4*4+3] + sh[j4*4+3], 0.f);
                *(float4*)&io[(size_t)m * 256 + tx * 16 + j4 * 4] = o;
            }
        }
    }
}

__global__ void k_wsfail(float* out, float val) {
    if (threadIdx.x == 0 && blockIdx.x == 0) out[0] = val;
}

// ---------- launch ----------
extern "C" void kernel_launch(void* const* d_in, const int* in_sizes, int n_in,
                              void* d_out, int out_size, void* d_ws, size_t ws_size,
                              hipStream_t stream) {
    const void* x     = d_in[0];
    const int*  ei    = (const int*)d_in[1];
    const void* W     = d_in[2];
    const void* b     = d_in[3];
    const void* gamma = d_in[4];
    const void* beta  = d_in[5];
    const void* rmean = d_in[6];
    const void* rvar  = d_in[7];

    int N = in_sizes[0] / 256;
    int E = in_sizes[1] / 2;
    float* out = (float*)d_out;

    char* w = (char*)d_ws;
    size_t used = 0;
    auto alloc = [&](size_t bytes) {
        char* p = w + used;
        used += (bytes + 255) & ~(size_t)255;
        return p;
    };
    int*   deg     = (int*)  alloc((size_t)N * 4);     // zeroed
    size_t zero_bytes = used;
    int*   row_off = (int*)  alloc((size_t)(N + 1) * 4);
    int*   cursor  = (int*)  alloc((size_t)N * 4);
    int*   bsum    = (int*)  alloc(256 * 4);
    int*   flags   = (int*)  alloc(256);
    float* dinv    = (float*)alloc((size_t)N * 4);
    int*   ssrc    = (int*)  alloc((size_t)E * 4);
    float* scale   = (float*)alloc(256 * 4);
    float* shift   = (float*)alloc(256 * 4);
    float* Wf      = (float*)alloc(256 * 256 * 4);
    unsigned short* Wt = (unsigned short*)alloc(256 * 256 * 2);
    size_t base_used = used;
    int*   rank    = (int*)  alloc((size_t)E * 4);
    unsigned short* aggw = (unsigned short*)alloc((size_t)N * 256 * 2);
    size_t tierB_used = used;
    unsigned short* xbf = (unsigned short*)alloc((size_t)N * 256 * 2);
    size_t tierA_used = used;
    int tA = (ws_size >= tierA_used) ? 1 : 0;
    int tB = (ws_size >= tierB_used) ? 1 : 0;

    if (ws_size < base_used) {
        k_wsfail<<<1, 64, 0, stream>>>(out, 9.0e7f + (float)(ws_size >> 10));
        return;
    }

    int C = (N + 255) / 256;
    const unsigned* xw = (const unsigned*)x;

    // ---- primary: single cooperative mega-kernel (tier A, C<=256) ----
    if (tA && C <= 256) {
        void* args[] = {
            (void*)&ei, (void*)&E, (void*)&N, (void*)&C,
            (void*)&flags, (void*)&deg, (void*)&rank, (void*)&row_off, (void*)&cursor,
            (void*)&bsum, (void*)&dinv, (void*)&ssrc,
            (void*)&xw, (void*)&xbf,
            (void*)&W, (void*)&b, (void*)&gamma, (void*)&beta,
            (void*)&rmean, (void*)&rvar,
            (void*)&Wf, (void*)&Wt, (void*)&scale, (void*)&shift,
            (void*)&aggw, (void*)&out };
        hipError_t err = hipLaunchCooperativeKernel((const void*)k_mega,
                                                    dim3(1024), dim3(256),
                                                    args, 0, stream);
        if (err == hipSuccess) return;
        // fall through to multi-dispatch path on failure
    }

    // ---- fallback: R6-proven multi-dispatch path ----
    int zwords = (int)(zero_bytes / 4);
    int gZ = (zwords + 255) / 256; if (gZ < 1) gZ = 1;
    k_init<<<gZ, 256, 0, stream>>>(deg, zwords, ei, xw,
                                   (const unsigned*)W, (const unsigned*)gamma, flags);

    int gE = (E + 255) / 256;
    int gC = (int)(((size_t)N * 32 + 255) / 256);
    int gH = tA ? (gE > gC ? gE : gC) : gE;
    k_hist_cvt<<<gH, 256, 0, stream>>>(ei, E, flags, N, deg, tB ? rank : cursor,
                                       xw, xbf, tA);

    k_scan1<<<256, 256, 0, stream>>>(deg, N, C, bsum);
    k_scan3<<<256, 256, 0, stream>>>(deg, bsum, N, C, row_off, cursor, dinv);

    int gEp = tB ? gE : 0;
    k_fuse_pp<<<256 + gEp, 256, 0, stream>>>(
        ei, E, flags, N, row_off, rank, ssrc,
        W, b, gamma, beta, rmean, rvar, Wf, Wt, scale, shift);

    if (!tB)
        k_scatter<<<gE, 256, 0, stream>>>(ei, E, flags, N, cursor, ssrc);

    if (tB) {
        k_agg_bf<<<(N + 3) / 4, 256, 0, stream>>>(tA ? (const void*)xbf : x, flags,
                                                  row_off, ssrc, dinv, aggw, N, tA);
        k_gemm_mfma<<<(N + 63) / 64, 256, 0, stream>>>(aggw, out, Wt, scale, shift, N);
    } else {
        k_agg<<<(N + 3) / 4, 256, 0, stream>>>(x, flags, row_off, ssrc, dinv, out, N);
        k_gemm32<<<(N + 63) / 64, 256, 0, stream>>>(out, Wf, scale, shift, N);
    }
}

// Round 8
// 251.891 us; speedup vs baseline: 3.8284x; 3.8284x over previous
//
#include <hip/hip_runtime.h>

// ---------- helpers ----------
__device__ inline unsigned short f2bf(float f) {
    unsigned u = __float_as_uint(f);
    unsigned r = u + 0x7FFF + ((u >> 16) & 1);   // round-to-nearest-even
    return (unsigned short)(r >> 16);
}
__device__ inline unsigned pk2bf(unsigned lo_bits, unsigned hi_bits) {
    unsigned rl = lo_bits + 0x7FFF + ((lo_bits >> 16) & 1);
    unsigned rh = hi_bits + 0x7FFF + ((hi_bits >> 16) & 1);
    return (rl >> 16) | (rh & 0xFFFF0000u);
}
__device__ inline float b2f(unsigned short h) { return __uint_as_float(((unsigned)h) << 16); }
__device__ inline float bfu_lo(unsigned u) { return __uint_as_float(u << 16); }
__device__ inline float bfu_hi(unsigned u) { return __uint_as_float(u & 0xFFFF0000u); }

typedef short bf16x8 __attribute__((ext_vector_type(8)));
typedef float f32x4  __attribute__((ext_vector_type(4)));

#define BN_EPS 1e-5f

// flags[0]=edges_are_int64, flags[1]=x_is_bf16, flags[2]=W_is_bf16, flags[3]=params_are_bf16

__device__ inline int edge_at(const int* ei32, int e64, long long idx) {
    if (e64) return (int)((const long long*)ei32)[idx];
    return ei32[idx];
}
__device__ inline float ldf(const void* p, int idx, int isbf) {
    return isbf ? b2f(((const unsigned short*)p)[idx]) : ((const float*)p)[idx];
}

// ---------- shared device bodies ----------
__device__ inline void hist_body(const int* ei32, int E, int e64, int N,
                                 int* cnt, int* rank, long long i) {
    if (i < E) {
        int s = edge_at(ei32, e64, i);
        int d = edge_at(ei32, e64, (long long)E + i);
        if ((unsigned)s < (unsigned)N && (unsigned)d < (unsigned)N)
            rank[i] = atomicAdd(&cnt[d], 1);
    }
}

__device__ inline void cvt_body_row(long long i, const unsigned* xw,
                                    unsigned short* xbf, int xisbf, long long nv) {
    if (i >= nv) return;
    if (xisbf) {
        ((uint4*)xbf)[i] = ((const uint4*)xw)[i];
    } else {
        const uint4* xp = (const uint4*)xw;
        uint4 a = xp[2 * i], b = xp[2 * i + 1];
        uint4 o;
        o.x = pk2bf(a.x, a.y);
        o.y = pk2bf(a.z, a.w);
        o.z = pk2bf(b.x, b.y);
        o.w = pk2bf(b.z, b.w);
        ((uint4*)xbf)[i] = o;
    }
}

__device__ inline void place_body(const int* ei32, int E, int e64, int N,
                                  const int* row_off, const int* rank, int* ssrc,
                                  long long i) {
    if (i < E) {
        int s = edge_at(ei32, e64, i);
        int d = edge_at(ei32, e64, (long long)E + i);
        if ((unsigned)s < (unsigned)N && (unsigned)d < (unsigned)N)
            ssrc[row_off[d] + rank[i]] = s;
    }
}

__device__ inline void prepw_body(const void* W, const void* b,
                                  const void* gamma, const void* beta,
                                  const void* rmean, const void* rvar,
                                  const int* flags,
                                  float* Wf, unsigned short* Wt,
                                  float* scale, float* shift, int k, int n) {
    int wbf = flags[2], pbf = flags[3];
    float wv = ldf(W, k * 256 + n, wbf);
    Wf[k * 256 + n] = wv;
    Wt[n * 256 + k] = f2bf(wv);
    if (k == 0) {
        float s = ldf(gamma, n, pbf) * rsqrtf(ldf(rvar, n, pbf) + BN_EPS);
        scale[n] = s;
        shift[n] = (ldf(b, n, pbf) - ldf(rmean, n, pbf)) * s + ldf(beta, n, pbf);
    }
}

// one row of the aggregation (R6-proven bf16 shuffle gather), result -> 8 bf16/lane packed
// stores into dst (global aggw row OR LDS row), both uint4-addressable.
__device__ inline void agg_row_core(const unsigned short* xs, const int* row_off,
                                    const int* ssrc, const float* dinv,
                                    int i, int lane, uint4* dst32 /*32 x uint4*/) {
    int half = lane >> 5, hl = lane & 31;
    int beg = row_off[i], end = row_off[i + 1];
    float di = dinv[i];
    float acc[8] = {};
    for (int base = beg; base < end; base += 64) {
        int cnt = end - base; if (cnt > 64) cnt = 64;
        int sl = 0; float dl = 0.f;
        if (lane < cnt) { sl = ssrc[base + lane]; dl = dinv[sl]; }
        for (int j = 0; j < cnt; j += 8) {
            int jj0 = j + half, jj1 = j + 2 + half, jj2 = j + 4 + half, jj3 = j + 6 + half;
            int   s0 = __shfl(sl, jj0 & 63), s1 = __shfl(sl, jj1 & 63);
            int   s2 = __shfl(sl, jj2 & 63), s3 = __shfl(sl, jj3 & 63);
            float d0 = __shfl(dl, jj0 & 63), d1 = __shfl(dl, jj1 & 63);
            float d2 = __shfl(dl, jj2 & 63), d3 = __shfl(dl, jj3 & 63);
            if (jj0 >= cnt) d0 = 0.f;
            if (jj1 >= cnt) d1 = 0.f;
            if (jj2 >= cnt) d2 = 0.f;
            if (jj3 >= cnt) d3 = 0.f;
            uint4 v0 = ((const uint4*)(xs + (size_t)s0 * 256))[hl];
            uint4 v1 = ((const uint4*)(xs + (size_t)s1 * 256))[hl];
            uint4 v2 = ((const uint4*)(xs + (size_t)s2 * 256))[hl];
            uint4 v3 = ((const uint4*)(xs + (size_t)s3 * 256))[hl];
            acc[0] += d0 * bfu_lo(v0.x); acc[1] += d0 * bfu_hi(v0.x);
            acc[2] += d0 * bfu_lo(v0.y); acc[3] += d0 * bfu_hi(v0.y);
            acc[4] += d0 * bfu_lo(v0.z); acc[5] += d0 * bfu_hi(v0.z);
            acc[6] += d0 * bfu_lo(v0.w); acc[7] += d0 * bfu_hi(v0.w);
            acc[0] += d1 * bfu_lo(v1.x); acc[1] += d1 * bfu_hi(v1.x);
            acc[2] += d1 * bfu_lo(v1.y); acc[3] += d1 * bfu_hi(v1.y);
            acc[4] += d1 * bfu_lo(v1.z); acc[5] += d1 * bfu_hi(v1.z);
            acc[6] += d1 * bfu_lo(v1.w); acc[7] += d1 * bfu_hi(v1.w);
            acc[0] += d2 * bfu_lo(v2.x); acc[1] += d2 * bfu_hi(v2.x);
            acc[2] += d2 * bfu_lo(v2.y); acc[3] += d2 * bfu_hi(v2.y);
            acc[4] += d2 * bfu_lo(v2.z); acc[5] += d2 * bfu_hi(v2.z);
            acc[6] += d2 * bfu_lo(v2.w); acc[7] += d2 * bfu_hi(v2.w);
            acc[0] += d3 * bfu_lo(v3.x); acc[1] += d3 * bfu_hi(v3.x);
            acc[2] += d3 * bfu_lo(v3.y); acc[3] += d3 * bfu_hi(v3.y);
            acc[4] += d3 * bfu_lo(v3.z); acc[5] += d3 * bfu_hi(v3.z);
            acc[6] += d3 * bfu_lo(v3.w); acc[7] += d3 * bfu_hi(v3.w);
        }
    }
    #pragma unroll
    for (int f = 0; f < 8; f++) acc[f] += __shfl(acc[f], lane ^ 32);
    if (half == 0) {
        uint4 v = ((const uint4*)(xs + (size_t)i * 256))[hl];
        float sv[8];
        sv[0] = bfu_lo(v.x); sv[1] = bfu_hi(v.x); sv[2] = bfu_lo(v.y); sv[3] = bfu_hi(v.y);
        sv[4] = bfu_lo(v.z); sv[5] = bfu_hi(v.z); sv[6] = bfu_lo(v.w); sv[7] = bfu_hi(v.w);
        unsigned short o[8];
        #pragma unroll
        for (int f = 0; f < 8; f++) o[f] = f2bf((acc[f] + di * sv[f]) * di);
        uint4 pk;
        pk.x = (unsigned)o[0] | ((unsigned)o[1] << 16);
        pk.y = (unsigned)o[2] | ((unsigned)o[3] << 16);
        pk.z = (unsigned)o[4] | ((unsigned)o[5] << 16);
        pk.w = (unsigned)o[6] | ((unsigned)o[7] << 16);
        dst32[hl] = pk;
    }
}

// ---------- K0: zero deg + dtype detect in block 0 ----------
__global__ void k_init(int* __restrict__ zb, int zwords,
                       const int* __restrict__ ei32,
                       const unsigned* __restrict__ xw,
                       const unsigned* __restrict__ Ww,
                       const unsigned* __restrict__ gw,
                       int* __restrict__ flags) {
    int gid = blockIdx.x * 256 + threadIdx.x;
    if (gid < zwords) zb[gid] = 0;
    if (blockIdx.x == 0) {
        __shared__ int s_nz, s_xc, s_wc;
        int t = threadIdx.x;
        if (t == 0) { s_nz = 0; s_xc = 0; s_wc = 0; }
        __syncthreads();
        int nz = 0, xc = 0, wc = 0;
        for (int i = t; i < 1024; i += 256)
            if (ei32[2 * i + 1] != 0) nz = 1;
        for (int i = t; i < 4096; i += 256) {
            unsigned ex = (xw[i] >> 7) & 0xFF;
            if (ex >= 90 && ex <= 150) xc++;
            unsigned ew = (Ww[i] >> 7) & 0xFF;
            if (ew >= 90 && ew <= 150) wc++;
        }
        atomicAdd(&s_xc, xc);
        atomicAdd(&s_wc, wc);
        if (nz) atomicOr(&s_nz, 1);
        __syncthreads();
        if (t == 0) {
            flags[0] = s_nz ? 0 : 1;
            int xbf = (s_xc > 3686) ? 1 : 0;
            int wbf = (s_wc > 3686) ? 1 : 0;
            flags[1] = xbf;
            flags[2] = wbf;
            unsigned g = gw[0];
            flags[3] = (g == 0x3F803F80u) ? 1 : ((g == 0x3F800000u) ? 0 : xbf);
        }
    }
}

// ---------- K1: histogram + rank fused with row-major x->bf16 cvt ----------
__global__ void k_hist_cvt(const int* __restrict__ ei32, int E, const int* __restrict__ flags,
                           int N, int* __restrict__ cnt, int* __restrict__ rank,
                           const unsigned* __restrict__ xw, unsigned short* __restrict__ xbf,
                           int do_cvt) {
    long long i = (long long)blockIdx.x * blockDim.x + threadIdx.x;
    hist_body(ei32, E, flags[0], N, cnt, rank, i);
    if (do_cvt) cvt_body_row(i, xw, xbf, flags[1], (long long)N * 32);
}

// ---------- K2a/b: scan (R6-proven) ----------
__global__ void k_scan1(const int* __restrict__ cnt, int N, int C, int* __restrict__ bsum) {
    __shared__ int sm[256];
    int b = blockIdx.x, t = threadIdx.x;
    int i = b * C + t;
    int v = (t < C && i < N) ? cnt[i] : 0;
    sm[t] = v;
    __syncthreads();
    for (int d = 128; d > 0; d >>= 1) {
        if (t < d) sm[t] += sm[t + d];
        __syncthreads();
    }
    if (t == 0) bsum[b] = sm[0];
}

__global__ void k_scan3(const int* __restrict__ cnt, const int* __restrict__ bsum,
                        int N, int C, int* __restrict__ row_off,
                        int* __restrict__ cursor, float* __restrict__ dinv) {
    __shared__ int sm[256];
    __shared__ int bs[256];
    int b = blockIdx.x, t = threadIdx.x;
    bs[t] = bsum[t];
    int i = b * C + t;
    int v = (t < C && i < N) ? cnt[i] : 0;
    sm[t] = v;
    for (int d = 1; d < 256; d <<= 1) {
        __syncthreads();
        int u  = (t >= d) ? bs[t - d] : 0;
        int u2 = (t >= d) ? sm[t - d] : 0;
        __syncthreads();
        bs[t] += u;
        sm[t] += u2;
    }
    __syncthreads();
    if (b == 0 && t == 255) row_off[N] = bs[255];
    int bbase = (b > 0) ? bs[b - 1] : 0;
    if (t < C && i < N) {
        int off = bbase + sm[t] - v;
        row_off[i] = off;
        cursor[i]  = off;
        dinv[i]    = rsqrtf((float)(v + 1));
    }
}

// ---------- K3: prepw | place ----------
__global__ void k_fuse_pp(const int* __restrict__ ei32, int E, const int* __restrict__ flags,
                          int N, const int* __restrict__ row_off, const int* __restrict__ rank,
                          int* __restrict__ ssrc,
                          const void* __restrict__ W, const void* __restrict__ b,
                          const void* __restrict__ gamma, const void* __restrict__ beta,
                          const void* __restrict__ rmean, const void* __restrict__ rvar,
                          float* __restrict__ Wf, unsigned short* __restrict__ Wt,
                          float* __restrict__ scale, float* __restrict__ shift) {
    int bb = blockIdx.x;
    if (bb < 256) {
        prepw_body(W, b, gamma, beta, rmean, rvar, flags, Wf, Wt, scale, shift,
                   bb, threadIdx.x);
    } else {
        long long i = (long long)(bb - 256) * 256 + threadIdx.x;
        place_body(ei32, E, flags[0], N, row_off, rank, ssrc, i);
    }
}

__global__ void k_scatter(const int* __restrict__ ei32, int E, const int* __restrict__ flags,
                          int N, int* __restrict__ cursor, int* __restrict__ ssrc) {
    int i = blockIdx.x * blockDim.x + threadIdx.x;
    if (i < E) {
        int e64 = flags[0];
        int s = edge_at(ei32, e64, i);
        int d = edge_at(ei32, e64, (long long)E + i);
        if ((unsigned)s < (unsigned)N && (unsigned)d < (unsigned)N) {
            int pos = atomicAdd(&cursor[d], 1);
            ssrc[pos] = s;
        }
    }
}

// ---------- K5+K6 FUSED: aggregate 64 rows into LDS, then MFMA GEMM from LDS ----------
// 512 threads = 8 waves; each wave aggregates 8 rows (R6-proven gather body)
// writing the bf16 result row into the GEMM A-tile in LDS. One barrier, then
// the proven MFMA tile: 8 waves x 32 cols, B streamed from L2-hot Wt.
// Saves the aggw global round-trip (25 MB write + 25.6 MB read) + 1 dispatch.
__global__ __launch_bounds__(512) void k_aggemm(
        const unsigned short* __restrict__ xbf,
        const int* __restrict__ row_off, const int* __restrict__ ssrc,
        const float* __restrict__ dinv,
        const unsigned short* __restrict__ Wt,
        const float* __restrict__ scale, const float* __restrict__ shift,
        float* __restrict__ out, int N) {
    __shared__ unsigned short Asm[64 * 264];
    int t = threadIdx.x;
    int m0 = blockIdx.x * 64;
    int wave = t >> 6, lane = t & 63;

    // --- phase 1: aggregation into LDS A-tile ---
    for (int k = 0; k < 8; k++) {
        int lr = wave * 8 + k;
        int i = m0 + lr;
        if (i < N) {
            agg_row_core(xbf, row_off, ssrc, dinv, i, lane,
                         (uint4*)&Asm[lr * 264]);
        } else if ((lane >> 5) == 0) {
            int hl = lane & 31;
            *(uint4*)&Asm[lr * 264 + hl * 8] = make_uint4(0u, 0u, 0u, 0u);
        }
    }
    __syncthreads();

    // --- phase 2: MFMA GEMM + BN + ReLU (A from LDS, B from global Wt) ---
    f32x4 acc[4][2] = {};
    int wc = wave * 32;
    int lm = lane & 15, q = lane >> 4;
    for (int k0 = 0; k0 < 256; k0 += 32) {
        bf16x8 af[4], bfr[2];
        for (int c = 0; c < 2; c++)
            bfr[c] = *(const bf16x8*)&Wt[(size_t)(wc + c * 16 + lm) * 256 + k0 + q * 8];
        for (int r = 0; r < 4; r++)
            af[r] = *(const bf16x8*)&Asm[(r * 16 + lm) * 264 + k0 + q * 8];
        for (int r = 0; r < 4; r++)
            for (int c = 0; c < 2; c++)
                acc[r][c] = __builtin_amdgcn_mfma_f32_16x16x32_bf16(af[r], bfr[c], acc[r][c], 0, 0, 0);
    }
    for (int c = 0; c < 2; c++) {
        int n = wc + c * 16 + lm;
        float sc = scale[n], sh = shift[n];
        for (int r = 0; r < 4; r++)
            for (int e = 0; e < 4; e++) {
                int m = m0 + r * 16 + q * 4 + e;
                if (m < N) {
                    float v = acc[r][c][e] * sc + sh;
                    out[(size_t)m * 256 + n] = fmaxf(v, 0.f);
                }
            }
    }
}

// ---------- tier-B fallback: separate agg + gemm (R6-proven) ----------
__global__ __launch_bounds__(256) void k_agg_bf(
        const void* __restrict__ xraw, const int* __restrict__ flags,
        const int* __restrict__ row_off, const int* __restrict__ ssrc,
        const float* __restrict__ dinv, unsigned short* __restrict__ aggw,
        int N, int force_bf) {
    int wave = threadIdx.x >> 6;
    int lane = threadIdx.x & 63;
    int half = lane >> 5, hl = lane & 31;
    int i = blockIdx.x * 4 + wave;
    if (i >= N) return;
    int xbf = force_bf ? 1 : flags[1];
    if (xbf) {
        agg_row_core((const unsigned short*)xraw, row_off, ssrc, dinv, i, lane,
                     (uint4*)(aggw + (size_t)i * 256));
        return;
    }
    int beg = row_off[i], end = row_off[i + 1];
    float di = dinv[i];
    float acc[8] = {};
    const float* xf = (const float*)xraw;
    for (int base = beg; base < end; base += 64) {
        int cnt = end - base; if (cnt > 64) cnt = 64;
        int sl = 0; float dl = 0.f;
        if (lane < cnt) { sl = ssrc[base + lane]; dl = dinv[sl]; }
        for (int j = 0; j < cnt; j += 4) {
            int jj0 = j + half, jj1 = j + 2 + half;
            int   s0 = __shfl(sl, jj0 & 63);
            float d0 = __shfl(dl, jj0 & 63);
            int   s1 = __shfl(sl, jj1 & 63);
            float d1 = __shfl(dl, jj1 & 63);
            if (jj0 >= cnt) d0 = 0.f;
            if (jj1 >= cnt) d1 = 0.f;
            const float4* p0 = (const float4*)(xf + (size_t)s0 * 256 + hl * 8);
            const float4* p1 = (const float4*)(xf + (size_t)s1 * 256 + hl * 8);
            float4 a0 = p0[0], a1 = p0[1];
            float4 b0 = p1[0], b1 = p1[1];
            acc[0] += d0 * a0.x; acc[1] += d0 * a0.y;
            acc[2] += d0 * a0.z; acc[3] += d0 * a0.w;
            acc[4] += d0 * a1.x; acc[5] += d0 * a1.y;
            acc[6] += d0 * a1.z; acc[7] += d0 * a1.w;
            acc[0] += d1 * b0.x; acc[1] += d1 * b0.y;
            acc[2] += d1 * b0.z; acc[3] += d1 * b0.w;
            acc[4] += d1 * b1.x; acc[5] += d1 * b1.y;
            acc[6] += d1 * b1.z; acc[7] += d1 * b1.w;
        }
    }
    #pragma unroll
    for (int f = 0; f < 8; f++) acc[f] += __shfl(acc[f], lane ^ 32);
    if (half == 0) {
        const float4* vp = (const float4*)(xf + (size_t)i * 256 + hl * 8);
        float4 v0 = vp[0], v1 = vp[1];
        float sv[8] = {v0.x, v0.y, v0.z, v0.w, v1.x, v1.y, v1.z, v1.w};
        unsigned short o[8];
        #pragma unroll
        for (int f = 0; f < 8; f++) o[f] = f2bf((acc[f] + di * sv[f]) * di);
        uint4 pk;
        pk.x = (unsigned)o[0] | ((unsigned)o[1] << 16);
        pk.y = (unsigned)o[2] | ((unsigned)o[3] << 16);
        pk.z = (unsigned)o[4] | ((unsigned)o[5] << 16);
        pk.w = (unsigned)o[6] | ((unsigned)o[7] << 16);
        ((uint4*)(aggw + (size_t)i * 256))[hl] = pk;
    }
}

__global__ __launch_bounds__(256) void k_gemm_mfma(
        const unsigned short* __restrict__ agg, float* __restrict__ out,
        const unsigned short* __restrict__ Wt,
        const float* __restrict__ scale, const float* __restrict__ shift, int N) {
    __shared__ unsigned short Asm[64 * 264];
    int t = threadIdx.x;
    int m0 = blockIdx.x * 64;
    for (int rep = 0; rep < 8; rep++) {
        int idx = rep * 256 + t;
        int r = idx >> 5, c8 = idx & 31;
        int m = m0 + r;
        uint4 v = make_uint4(0u, 0u, 0u, 0u);
        if (m < N) v = ((const uint4*)(agg + (size_t)m * 256))[c8];
        *(uint4*)&Asm[r * 264 + c8 * 8] = v;
    }
    __syncthreads();
    f32x4 acc[4][4] = {};
    int wv = t >> 6, lane = t & 63;
    int wc = wv * 64;
    int lm = lane & 15, q = lane >> 4;
    for (int k0 = 0; k0 < 256; k0 += 32) {
        bf16x8 af[4], bfr[4];
        for (int c = 0; c < 4; c++)
            bfr[c] = *(const bf16x8*)&Wt[(size_t)(wc + c * 16 + lm) * 256 + k0 + q * 8];
        for (int r = 0; r < 4; r++)
            af[r] = *(const bf16x8*)&Asm[(r * 16 + lm) * 264 + k0 + q * 8];
        for (int r = 0; r < 4; r++)
            for (int c = 0; c < 4; c++)
                acc[r][c] = __builtin_amdgcn_mfma_f32_16x16x32_bf16(af[r], bfr[c], acc[r][c], 0, 0, 0);
    }
    for (int c = 0; c < 4; c++) {
        int n = wc + c * 16 + lm;
        float sc = scale[n], sh = shift[n];
        for (int r = 0; r < 4; r++)
            for (int e = 0; e < 4; e++) {
                int m = m0 + r * 16 + q * 4 + e;
                if (m < N) {
                    float v = acc[r][c][e] * sc + sh;
                    out[(size_t)m * 256 + n] = fmaxf(v, 0.f);
                }
            }
    }
}

// ---------- base fallback: f32 agg + VALU gemm ----------
__global__ __launch_bounds__(256) void k_agg(
        const void* __restrict__ xraw, const int* __restrict__ flags,
        const int* __restrict__ row_off, const int* __restrict__ ssrc,
        const float* __restrict__ dinv, float* __restrict__ out, int N) {
    int wave = threadIdx.x >> 6;
    int lane = threadIdx.x & 63;
    int i = blockIdx.x * 4 + wave;
    if (i >= N) return;
    int beg = row_off[i], end = row_off[i + 1];
    float di = dinv[i];
    float a0, a1, a2, a3;
    if (flags[1]) {
        const unsigned short* xs = (const unsigned short*)xraw;
        uint2 sv = ((const uint2*)(xs + (size_t)i * 256))[lane];
        a0 = di * bfu_lo(sv.x); a1 = di * bfu_hi(sv.x);
        a2 = di * bfu_lo(sv.y); a3 = di * bfu_hi(sv.y);
        for (int base = beg; base < end; base += 64) {
            int cnt = end - base; if (cnt > 64) cnt = 64;
            int sl = 0; float dl = 0.f;
            if (lane < cnt) { sl = ssrc[base + lane]; dl = dinv[sl]; }
            for (int j = 0; j < cnt; j++) {
                int   s  = __shfl(sl, j);
                float ds = __shfl(dl, j);
                uint2 v = ((const uint2*)(xs + (size_t)s * 256))[lane];
                a0 += ds * bfu_lo(v.x); a1 += ds * bfu_hi(v.x);
                a2 += ds * bfu_lo(v.y); a3 += ds * bfu_hi(v.y);
            }
        }
    } else {
        const float* xf = (const float*)xraw;
        float4 sv = ((const float4*)(xf + (size_t)i * 256))[lane];
        a0 = di * sv.x; a1 = di * sv.y; a2 = di * sv.z; a3 = di * sv.w;
        for (int base = beg; base < end; base += 64) {
            int cnt = end - base; if (cnt > 64) cnt = 64;
            int sl = 0; float dl = 0.f;
            if (lane < cnt) { sl = ssrc[base + lane]; dl = dinv[sl]; }
            for (int j = 0; j < cnt; j++) {
                int   s  = __shfl(sl, j);
                float ds = __shfl(dl, j);
                float4 v = ((const float4*)(xf + (size_t)s * 256))[lane];
                a0 += ds * v.x; a1 += ds * v.y; a2 += ds * v.z; a3 += ds * v.w;
            }
        }
    }
    float4 o;
    o.x = a0 * di; o.y = a1 * di; o.z = a2 * di; o.w = a3 * di;
    ((float4*)(out + (size_t)i * 256))[lane] = o;
}

__global__ __launch_bounds__(256) void k_gemm32(
        float* __restrict__ io, const float* __restrict__ Wf,
        const float* __restrict__ scale, const float* __restrict__ shift, int N) {
    __shared__ float Asm[64][17];
    __shared__ float Wsm[16][260];
    int t = threadIdx.x;
    int m0 = blockIdx.x * 64;
    int tx = t & 15, ty = t >> 4;
    float acc[4][16] = {};
    for (int k0 = 0; k0 < 256; k0 += 16) {
        __syncthreads();
        {
            int r = t >> 2, c = (t & 3) * 4;
            int m = m0 + r;
            float4 v = make_float4(0.f, 0.f, 0.f, 0.f);
            if (m < N) v = *(const float4*)&io[(size_t)m * 256 + k0 + c];
            Asm[r][c] = v.x; Asm[r][c + 1] = v.y; Asm[r][c + 2] = v.z; Asm[r][c + 3] = v.w;
        }
        {
            int kk = t >> 4, nn = (t & 15) * 16;
            const float4* g = (const float4*)&Wf[(size_t)(k0 + kk) * 256 + nn];
            float4 w0 = g[0], w1 = g[1], w2 = g[2], w3 = g[3];
            *(float4*)&Wsm[kk][nn]      = w0;
            *(float4*)&Wsm[kk][nn + 4]  = w1;
            *(float4*)&Wsm[kk][nn + 8]  = w2;
            *(float4*)&Wsm[kk][nn + 12] = w3;
        }
        __syncthreads();
        #pragma unroll
        for (int kk = 0; kk < 16; kk++) {
            float av[4] = {Asm[ty*4+0][kk], Asm[ty*4+1][kk], Asm[ty*4+2][kk], Asm[ty*4+3][kk]};
            float4 b0 = *(const float4*)&Wsm[kk][tx * 16];
            float4 b1 = *(const float4*)&Wsm[kk][tx * 16 + 4];
            float4 b2 = *(const float4*)&Wsm[kk][tx * 16 + 8];
            float4 b3 = *(const float4*)&Wsm[kk][tx * 16 + 12];
            float bv[16] = {b0.x,b0.y,b0.z,b0.w, b1.x,b1.y,b1.z,b1.w,
                            b2.x,b2.y,b2.z,b2.w, b3.x,b3.y,b3.z,b3.w};
            #pragma unroll
            for (int i = 0; i < 4; i++)
                #pragma unroll
                for (int j = 0; j < 16; j++)
                    acc[i][j] = fmaf(av[i], bv[j], acc[i][j]);
        }
    }
    float sc[16], sh[16];
    #pragma unroll
    for (int j = 0; j < 16; j++) { sc[j] = scale[tx * 16 + j]; sh[j] = shift[tx * 16 + j]; }
    for (int i = 0; i < 4; i++) {
        int m = m0 + ty * 4 + i;
        if (m < N) {
            #pragma unroll
            for (int j4 = 0; j4 < 4; j4++) {
                float4 o;
                o.x = fmaxf(acc[i][j4*4+0] * sc[j4*4+0] + sh[j4*4+0], 0.f);
                o.y = fmaxf(acc[i][j4*4+1] * sc[j4*4+1] + sh[j4*4+1], 0.f);
                o.z = fmaxf(acc[i][j4*4+2] * sc[j4*4+2] + sh[j4*4+2], 0.f);
                o.w = fmaxf(acc[i][j4*4+3] * sc[j4*4+3] + sh[j4*4+3], 0.f);
                *(float4*)&io[(size_t)m * 256 + tx * 16 + j4 * 4] = o;
            }
        }
    }
}

__global__ void k_wsfail(float* out, float val) {
    if (threadIdx.x == 0 && blockIdx.x == 0) out[0] = val;
}

// ---------- launch ----------
extern "C" void kernel_launch(void* const* d_in, const int* in_sizes, int n_in,
                              void* d_out, int out_size, void* d_ws, size_t ws_size,
                              hipStream_t stream) {
    const void* x     = d_in[0];
    const int*  ei    = (const int*)d_in[1];
    const void* W     = d_in[2];
    const void* b     = d_in[3];
    const void* gamma = d_in[4];
    const void* beta  = d_in[5];
    const void* rmean = d_in[6];
    const void* rvar  = d_in[7];

    int N = in_sizes[0] / 256;
    int E = in_sizes[1] / 2;
    float* out = (float*)d_out;

    char* w = (char*)d_ws;
    size_t used = 0;
    auto alloc = [&](size_t bytes) {
        char* p = w + used;
        used += (bytes + 255) & ~(size_t)255;
        return p;
    };
    int*   deg     = (int*)  alloc((size_t)N * 4);     // zeroed by k_init
    size_t zero_bytes = used;
    int*   row_off = (int*)  alloc((size_t)(N + 1) * 4);
    int*   cursor  = (int*)  alloc((size_t)N * 4);
    int*   bsum    = (int*)  alloc(256 * 4);
    int*   flags   = (int*)  alloc(256);
    float* dinv    = (float*)alloc((size_t)N * 4);
    int*   ssrc    = (int*)  alloc((size_t)E * 4);
    float* scale   = (float*)alloc(256 * 4);
    float* shift   = (float*)alloc(256 * 4);
    float* Wf      = (float*)alloc(256 * 256 * 4);
    unsigned short* Wt = (unsigned short*)alloc(256 * 256 * 2);
    size_t base_used = used;
    int*   rank    = (int*)  alloc((size_t)E * 4);
    unsigned short* aggw = (unsigned short*)alloc((size_t)N * 256 * 2);
    size_t tierB_used = used;
    unsigned short* xbf = (unsigned short*)alloc((size_t)N * 256 * 2);
    size_t tierA_used = used;
    int tA = (ws_size >= tierA_used) ? 1 : 0;   // rank + aggw + xbf
    int tB = (ws_size >= tierB_used) ? 1 : 0;   // rank + aggw

    if (ws_size < base_used) {
        k_wsfail<<<1, 64, 0, stream>>>(out, 9.0e7f + (float)(ws_size >> 10));
        return;
    }

    int C = (N + 255) / 256;

    // 1. zero deg + detect dtypes
    int zwords = (int)(zero_bytes / 4);
    int gZ = (zwords + 255) / 256; if (gZ < 1) gZ = 1;
    k_init<<<gZ, 256, 0, stream>>>(deg, zwords, ei, (const unsigned*)x,
                                   (const unsigned*)W, (const unsigned*)gamma, flags);

    // 2. histogram (+rank) fused with row-major x->bf16 cvt
    int gE = (E + 255) / 256;
    int gC = (int)(((size_t)N * 32 + 255) / 256);
    int gH = tA ? (gE > gC ? gE : gC) : gE;
    k_hist_cvt<<<gH, 256, 0, stream>>>(ei, E, flags, N, deg, tB ? rank : cursor,
                                       (const unsigned*)x, xbf, tA);

    // 3. scan -> row_off, cursor, dinv
    k_scan1<<<256, 256, 0, stream>>>(deg, N, C, bsum);
    k_scan3<<<256, 256, 0, stream>>>(deg, bsum, N, C, row_off, cursor, dinv);

    // 4. prepw | place
    int gEp = tB ? gE : 0;
    k_fuse_pp<<<256 + gEp, 256, 0, stream>>>(
        ei, E, flags, N, row_off, rank, ssrc,
        W, b, gamma, beta, rmean, rvar, Wf, Wt, scale, shift);

    if (!tB)
        k_scatter<<<gE, 256, 0, stream>>>(ei, E, flags, N, cursor, ssrc);

    // 5. fused aggregation + GEMM (tier A) or fallbacks
    if (tA) {
        k_aggemm<<<(N + 63) / 64, 512, 0, stream>>>(xbf, row_off, ssrc, dinv,
                                                    Wt, scale, shift, out, N);
    } else if (tB) {
        k_agg_bf<<<(N + 3) / 4, 256, 0, stream>>>(x, flags, row_off, ssrc, dinv, aggw, N, 0);
        k_gemm_mfma<<<(N + 63) / 64, 256, 0, stream>>>(aggw, out, Wt, scale, shift, N);
    } else {
        k_agg<<<(N + 3) / 4, 256, 0, stream>>>(x, flags, row_off, ssrc, dinv, out, N);
        k_gemm32<<<(N + 63) / 64, 256, 0, stream>>>(out, Wf, scale, shift, N);
    }
}